// Round 9
// baseline (405.125 us; speedup 1.0000x reference)
//
#include <hip/hip_runtime.h>
#include <math.h>

// LRU forward, SINGLE fused kernel (R9: barrier-free wave-private design).
//   cvt_w: weights->bf16 (Bw=[Bre;Bim] 1024x256, W2=[Cre|Cim|D] 256x1280), Ltab.
//   lru_mega: block = (batch b, 32-t chunk cIdx), 512 thr / 8 waves, grid 2048.
//     Tile 48 rows = 16 warmup + 32 own.  LDS: Xt 48x264 (25.3KB) +
//     Ht 48x1032 (99.1KB) = 124.4KB -> 1 block/CU.
//     KEY CHANGE vs R8: wave wv owns channel group wv END-TO-END:
//       - U-gemm for its 128 Ht cols (8 slabs of 16), writes wave-PRIVATE
//         Ht slice (no barrier needed before its own scan: lgkmcnt only)
//       - scan its group: lane = complex channel, 16-step warmup (err<=e^-16),
//         32 own rows updated in-place
//       - ONE block barrier, then Y-gemm: yac[32 rows][32 cols]/wave over
//         K=1024 (all groups' H) + 256 (D from Xt) -> f32 Y store.
//     Barriers per block: 34 (R8) -> 3.  Waves drift phase-independently ->
//     MFMA/VALU/mem overlap across waves instead of lockstep stalls.

#define T_LEN  4096
#define NBATCH 16
#define IN_D   256
#define OUT_D  256
#define HID    512
#define XT_STR 264        // Xt row stride (shorts); rows 16B aligned
#define HT_STR 1032       // Ht row stride (shorts); 8 groups x 128 + 8 pad

typedef __attribute__((ext_vector_type(8))) short short8;
typedef __attribute__((ext_vector_type(4))) float float4v;

static __device__ __forceinline__ unsigned short f2bf(float f) {
    union { float f; unsigned u; } v; v.f = f;
    unsigned r = v.u + 0x7FFFu + ((v.u >> 16) & 1u);   // RNE
    return (unsigned short)(r >> 16);
}
static __device__ __forceinline__ float bf2f(unsigned short h) {
    union { unsigned u; float f; } v; v.u = ((unsigned)h) << 16;
    return v.f;
}

// ---- ws layout (bytes) ----
// [0)        Bw  bf16 [1024][256]   524288
// [524288)   W2  bf16 [256][1280]   655360
// [1179648)  Ltab float4[512]       8192

__global__ __launch_bounds__(256) void cvt_w(
    const float* __restrict__ B_re, const float* __restrict__ B_im,
    const float* __restrict__ C_re, const float* __restrict__ C_im,
    const float* __restrict__ Dm, unsigned short* __restrict__ W)
{
    int e = (blockIdx.x * 256 + threadIdx.x) * 4;      // exact: 576 blocks
    const float* src; int off;
    if (e < 262144) {                                   // Bw = [Bre;Bim]
        if (e < 131072) { src = B_re; off = e; }
        else            { src = B_im; off = e - 131072; }
    } else {                                            // W2 rows: [Cre|Cim|D]
        int e2 = e - 262144;
        int row = e2 / 1280, c = e2 % 1280;
        if      (c < 512)  { src = C_re; off = row * 512 + c; }
        else if (c < 1024) { src = C_im; off = row * 512 + c - 512; }
        else               { src = Dm;   off = row * 256 + c - 1024; }
    }
    float4 v = *(const float4*)(src + off);
    ushort4 o;
    o.x = f2bf(v.x); o.y = f2bf(v.y); o.z = f2bf(v.z); o.w = f2bf(v.w);
    *(ushort4*)(W + e) = o;
}

__global__ __launch_bounds__(256) void lam_prep(
    const float* __restrict__ nu_log, const float* __restrict__ theta_log,
    const float* __restrict__ bh_re, float4* __restrict__ Ltab)
{
    int ch = blockIdx.x * 256 + threadIdx.x;
    if (ch >= HID) return;
    float mod = expf(-expf(nu_log[ch]));
    float th  = expf(theta_log[ch]);
    Ltab[ch] = make_float4(mod * cosf(th), mod * sinf(th),
                           sqrtf(fmaxf(0.f, 1.f - mod * mod)), bh_re[ch]);
}

// ---- the fused kernel: grid 2048 = 8 xcd x 256, block 512 / 8 waves ----
__global__ __launch_bounds__(512, 2) void lru_mega(
    const float* __restrict__ X, const unsigned short* __restrict__ Bw,
    const unsigned short* __restrict__ W2,
    const float4* __restrict__ Ltab, const float* __restrict__ bh_im,
    const float* __restrict__ bias_out,
    float* __restrict__ Y, float* __restrict__ hN, int hN_mode)
{
    __shared__ unsigned short Xt[48 * XT_STR];   // 25344 B
    __shared__ unsigned short Ht[48 * HT_STR];   // 99072 B  (total 124416)

    const int tid  = threadIdx.x;
    const int lane = tid & 63;
    const int wv   = tid >> 6;                   // 0..7 = channel group
    const int col  = lane & 15, quad = lane >> 4;

    // XCD swizzle: consecutive cIdx on same XCD (warmup rows overlap neighbor)
    const int bid  = blockIdx.x;
    const int xcd  = bid & 7;
    const int bc   = xcd * 256 + (bid >> 3);     // 0..2047
    const int b    = bc >> 7;                    // batch
    const int cIdx = bc & 127;                   // 32-t chunk in batch
    const int G0   = b * T_LEN + cIdx * 32;      // first output row
    const int bLo  = b * T_LEN;

    // ---- stage X rows G0-16 .. G0+31 -> Xt (bf16); 1KB row per wave-instr
#pragma unroll
    for (int i = 0; i < 6; ++i) {
        const int r = wv * 6 + i;                // 0..47
        int g = G0 - 16 + r; if (g < bLo) g = bLo;       // clamp (cIdx=0 only)
        float4 v = *(const float4*)(X + (size_t)g * IN_D + lane * 4);
        ushort4 o;
        o.x = f2bf(v.x); o.y = f2bf(v.y); o.z = f2bf(v.z); o.w = f2bf(v.w);
        *(ushort4*)(Xt + r * XT_STR + lane * 4) = o;
    }
    __syncthreads();

    // ---- U-gemm for OWN group wv: 8 slabs of 16 cols (re 0-3, im 4-7) ----
#pragma unroll
    for (int cs = 0; cs < 8; ++cs) {
        float4v ua[3];
#pragma unroll
        for (int i = 0; i < 3; ++i) ua[i] = (float4v)0.f;
        const int pw  = cs >> 2;                 // 0 re, 1 im
        const int chl = (cs & 3) * 16 + col;     // 0..63 within group
        const int ch  = wv * 64 + chl;
        const unsigned short* Brow =
            Bw + (size_t)(pw * 512 + ch) * IN_D + quad * 8;
#pragma unroll
        for (int ks = 0; ks < 8; ++ks) {
            short8 af[3], bfr;
#pragma unroll
            for (int mt = 0; mt < 3; ++mt)
                af[mt] = *(const short8*)(Xt + (mt * 16 + col) * XT_STR
                                          + ks * 32 + quad * 8);
            bfr = *(const short8*)(Brow + ks * 32);
#pragma unroll
            for (int mt = 0; mt < 3; ++mt)
                ua[mt] = __builtin_amdgcn_mfma_f32_16x16x32_bf16(
                    af[mt], bfr, ua[mt], 0, 0, 0);
        }
        // epilogue: U = gamma*(ua + bh) -> wave-private Ht slice
        float4 L = Ltab[ch];
        const float gam = L.z;
        const float bv  = pw ? bh_im[ch] : L.w;
        const int   cl  = wv * 128 + pw * 64 + chl;
#pragma unroll
        for (int mt = 0; mt < 3; ++mt)
#pragma unroll
            for (int r = 0; r < 4; ++r) {
                const int ml = mt * 16 + quad * 4 + r;
                Ht[ml * HT_STR + cl] = f2bf(gam * (ua[mt][r] + bv));
            }
    }
    // NO barrier: scan reads only this wave's own Ht slice (lgkmcnt suffices)

    // ---- scan own group: lane = complex channel ----
    {
        float4 L = Ltab[wv * 64 + lane];
        const float lre = L.x, lim = L.y, bre = L.w;
        const float bim = bh_im[wv * 64 + lane];
        const int cre = wv * 128 + lane, cim = cre + 64;
        float hre = 0.f, him = 0.f;
        const int warmBeg = (cIdx == 0) ? 16 : 0;
        for (int t0 = warmBeg; t0 < 16; t0 += 8) {       // warmup: reads only
            float ur[8], ui[8];
#pragma unroll
            for (int s = 0; s < 8; ++s) {
                ur[s] = bf2f(Ht[(t0 + s) * HT_STR + cre]);
                ui[s] = bf2f(Ht[(t0 + s) * HT_STR + cim]);
            }
#pragma unroll
            for (int s = 0; s < 8; ++s) {
                float nr = lre * hre - lim * him + ur[s] + bre;
                him      = lre * him + lim * hre + ui[s] + bim;
                hre = nr;
            }
        }
#pragma unroll
        for (int t0 = 16; t0 < 48; t0 += 8) {            // own rows: U -> H
            float ur[8], ui[8];
#pragma unroll
            for (int s = 0; s < 8; ++s) {
                ur[s] = bf2f(Ht[(t0 + s) * HT_STR + cre]);
                ui[s] = bf2f(Ht[(t0 + s) * HT_STR + cim]);
            }
#pragma unroll
            for (int s = 0; s < 8; ++s) {
                float nr = lre * hre - lim * him + ur[s] + bre;
                him      = lre * him + lim * hre + ui[s] + bim;
                hre = nr;
                Ht[(t0 + s) * HT_STR + cre] = f2bf(hre);
                Ht[(t0 + s) * HT_STR + cim] = f2bf(-him);
            }
        }
        if (hN_mode && cIdx == 127) {                    // h at t=4095
            const int ch = wv * 64 + lane;
            if (hN_mode == 2) {
                hN[((size_t)b * HID + ch) * 2]     = hre;
                hN[((size_t)b * HID + ch) * 2 + 1] = him;
            } else {
                hN[(size_t)b * HID + ch] = hre;
            }
        }
    }
    __syncthreads();                 // all groups' H complete

    // ---- Y-gemm: yac[32 rows][32 cols]/wave, K = 1024 (H) + 256 (D) ----
    float4v yac[4];
#pragma unroll
    for (int i = 0; i < 4; ++i) yac[i] = (float4v)0.f;
    const unsigned short* Wr0 = W2 + (size_t)(wv * 32 + col) * 1280 + quad * 8;
    const unsigned short* Wr1 = W2 + (size_t)(wv * 32 + 16 + col) * 1280 + quad * 8;

#pragma unroll
    for (int g = 0; g < 8; ++g) {
#pragma unroll
        for (int u = 0; u < 4; ++u) {            // (half, kk)
            const int half = u >> 1, kk = u & 1;
            const int hcol = g * 128 + half * 64 + kk * 32;
            const int wcol = half * 512 + g * 64 + kk * 32;
            short8 af[2], bf[2];
#pragma unroll
            for (int mt = 0; mt < 2; ++mt)
                af[mt] = *(const short8*)(Ht + (16 + mt * 16 + col) * HT_STR
                                          + hcol + quad * 8);
            bf[0] = *(const short8*)(Wr0 + wcol);
            bf[1] = *(const short8*)(Wr1 + wcol);
#pragma unroll
            for (int mt = 0; mt < 2; ++mt)
#pragma unroll
                for (int nt = 0; nt < 2; ++nt)
                    yac[mt * 2 + nt] = __builtin_amdgcn_mfma_f32_16x16x32_bf16(
                        af[mt], bf[nt], yac[mt * 2 + nt], 0, 0, 0);
        }
    }
    // D term from Xt rows 16..47
#pragma unroll
    for (int ks = 0; ks < 8; ++ks) {
        short8 af[2], bf[2];
#pragma unroll
        for (int mt = 0; mt < 2; ++mt)
            af[mt] = *(const short8*)(Xt + (16 + mt * 16 + col) * XT_STR
                                      + ks * 32 + quad * 8);
        bf[0] = *(const short8*)(Wr0 + 1024 + ks * 32);
        bf[1] = *(const short8*)(Wr1 + 1024 + ks * 32);
#pragma unroll
        for (int mt = 0; mt < 2; ++mt)
#pragma unroll
            for (int nt = 0; nt < 2; ++nt)
                yac[mt * 2 + nt] = __builtin_amdgcn_mfma_f32_16x16x32_bf16(
                    af[mt], bf[nt], yac[mt * 2 + nt], 0, 0, 0);
    }

    // ---- store Y (f32) + bias ----
#pragma unroll
    for (int nt = 0; nt < 2; ++nt) {
        const int o = wv * 32 + nt * 16 + col;
        const float bo = bias_out[o];
#pragma unroll
        for (int mt = 0; mt < 2; ++mt)
#pragma unroll
            for (int r = 0; r < 4; ++r) {
                const int m = G0 + mt * 16 + quad * 4 + r;
                Y[(size_t)m * OUT_D + o] = yac[mt * 2 + nt][r] + bo;
            }
    }
}

extern "C" void kernel_launch(void* const* d_in, const int* in_sizes, int n_in,
                              void* d_out, int out_size, void* d_ws, size_t ws_size,
                              hipStream_t stream) {
    const float* X        = (const float*)d_in[0];
    const float* nu_log   = (const float*)d_in[1];
    const float* theta_lg = (const float*)d_in[2];
    const float* B_re     = (const float*)d_in[3];
    const float* B_im     = (const float*)d_in[4];
    const float* C_re     = (const float*)d_in[5];
    const float* C_im     = (const float*)d_in[6];
    const float* Dm       = (const float*)d_in[7];
    const float* bh_re    = (const float*)d_in[8];
    const float* bh_im    = (const float*)d_in[9];
    const float* bias_out = (const float*)d_in[10];

    float* Y = (float*)d_out;
    const int YSZ = NBATCH * T_LEN * OUT_D;          // 16777216
    int extra = out_size - YSZ;
    int mode = (extra >= NBATCH * HID * 2) ? 2 : ((extra >= NBATCH * HID) ? 1 : 0);
    float* hN = Y + YSZ;

    char* ws = (char*)d_ws;
    unsigned short* W    = (unsigned short*)ws;                    // Bw + W2
    unsigned short* W2   = W + 262144;
    float4*         Ltab = (float4*)(ws + 1179648);

    cvt_w<<<dim3(576), 256, 0, stream>>>(B_re, B_im, C_re, C_im, Dm, W);
    lam_prep<<<dim3(2), 256, 0, stream>>>(nu_log, theta_lg, bh_re, Ltab);
    lru_mega<<<dim3(2048), 512, 0, stream>>>(X, W, W2, Ltab, bh_im, bias_out,
                                             Y, hN, mode);
}